// Round 7
// baseline (240.544 us; speedup 1.0000x reference)
//
#include <hip/hip_runtime.h>
#include <hip/hip_bf16.h>

#define NSTEPS 5
#define ABUFSZ 32768   // 512*64 floats per step buffer

typedef __attribute__((ext_vector_type(8))) short short8;
typedef __attribute__((ext_vector_type(4))) float floatx4;

static __device__ __forceinline__ unsigned pk2bf(float a, float b) {
    __hip_bfloat162 h = __float22bfloat162_rn(make_float2(a, b));
    return *reinterpret_cast<unsigned*>(&h);
}

// write-through store: data visible at device coherence point (no fence needed)
static __device__ __forceinline__ void store_wt4(float* addr, floatx4 v) {
    __asm__ volatile("global_store_dwordx4 %0, %1, off sc0 sc1"
                     :: "v"(addr), "v"(v) : "memory");
}

struct Params {
    const float *J, *b, *W1, *b1, *W2, *b2, *W3, *b3;
    const float *W_ih, *b_ih, *W_hh, *b_hh;
    const float *Wr1, *br1, *Wr2, *br2, *Wr3, *br3;
    float *out;
    float *aBase;          // NSTEPS rotating a-buffers (512x64 each)
    unsigned *bar;         // tree barrier state (monotonic counters)
};

// Monotonic tree grid barrier, 512 blocks, all-RELAXED atomics (no L2
// invalidates). Producer visibility from write-through stores + vmcnt(0).
// bar[g*16] g=0..7 group ctrs (64 blocks each), bar[128] master, bar[144] gen.
static __device__ __forceinline__ void gbar(unsigned* bar, unsigned ph) {
    __builtin_amdgcn_s_waitcnt(0);         // this wave's WT stores at coherence pt
    __syncthreads();                       // => all waves' stores done
    if (threadIdx.x == 0) {
        const int g = blockIdx.x & 7;
        unsigned old = __hip_atomic_fetch_add(&bar[g * 16], 1u, __ATOMIC_RELAXED,
                                              __HIP_MEMORY_SCOPE_AGENT);
        if (old == 64u * ph - 1u) {
            unsigned mo = __hip_atomic_fetch_add(&bar[128], 1u, __ATOMIC_RELAXED,
                                                 __HIP_MEMORY_SCOPE_AGENT);
            if (mo == 8u * ph - 1u)
                __hip_atomic_store(&bar[144], ph, __ATOMIC_RELAXED,
                                   __HIP_MEMORY_SCOPE_AGENT);
        }
        while (__hip_atomic_load(&bar[144], __ATOMIC_RELAXED,
                                 __HIP_MEMORY_SCOPE_AGENT) < ph)
            __builtin_amdgcn_s_sleep(2);
    }
    __syncthreads();
    __asm__ volatile("" ::: "memory");     // block load hoisting above barrier
}

__global__ __launch_bounds__(512, 4) void ggnn_fused(Params p)
{
    const int tid = threadIdx.x;
    const int l = tid & 63, w = tid >> 6;          // 8 waves
    const int m = l & 15, q = l >> 4;
    const int j = blockIdx.x;

    __shared__ __align__(16) float smJ[512];       // column j of J
    __shared__ __align__(16) float smB[512];       // b vector
    __shared__ __align__(16) float smW1hi[64][16];
    __shared__ __align__(16) float smW1hj[64][16];
    __shared__ __align__(16) float smwJ[64], smwbi[64], smwbj[64], smb1[64];
    __shared__ __align__(16) float smC[64];
    __shared__ __align__(16) float smA[64];
    __shared__ __align__(16) float smH[16];
    __shared__ __align__(16) float smWave[8][64];
    __shared__ __align__(16) float smMacc[64];
    __shared__ __align__(16) float smGin[48];      // [h(16), msg(32)]
    __shared__ __align__(16) float smGi[48], smGh[48];
    __shared__ __align__(16) float smY[64], smY2[64];
    __shared__ float smR[2];

    // ---- init: direct J-column gather + b + weights; no transpose, no barrier ----
    smJ[tid] = p.J[tid * 512 + j];                 // scattered, 1 load/thread
    smB[tid] = p.b[tid];
    if (tid < 64) {
        int o = tid;
        #pragma unroll
        for (int s = 0; s < 16; ++s) {
            smW1hi[o][s] = p.W1[o * 35 + s];
            smW1hj[o][s] = p.W1[o * 35 + 16 + s];
        }
        smwJ[o]  = p.W1[o * 35 + 32];
        smwbi[o] = p.W1[o * 35 + 33];
        smwbj[o] = p.W1[o * 35 + 34];
        smb1[o]  = p.b1[o];
    }

    short8 bfw[4][2];
    float b2n[4];
    {
        const floatx4* W2v = (const floatx4*)p.W2;
        #pragma unroll
        for (int nt = 0; nt < 4; ++nt) {
            int n = nt * 16 + m;
            #pragma unroll
            for (int ks = 0; ks < 2; ++ks) {
                int kb = ks * 32 + q * 8;
                floatx4 f0 = W2v[n * 16 + (kb >> 2)];
                floatx4 f1 = W2v[n * 16 + (kb >> 2) + 1];
                union { short8 s; unsigned u[4]; } t;
                t.u[0] = pk2bf(f0[0], f0[1]); t.u[1] = pk2bf(f0[2], f0[3]);
                t.u[2] = pk2bf(f1[0], f1[1]); t.u[3] = pk2bf(f1[2], f1[3]);
                bfw[nt][ks] = t.s;
            }
            b2n[nt] = p.b2[nt * 16 + m];
        }
    }
    __syncthreads();

    const float bj = smB[j];
    if (tid < 64) smC[tid] = bj * smwbj[tid] + smb1[tid];   // c0_j
    if (tid < 16) smH[tid] = 0.f;

    floatx4 wva, wvb, wvc, wvd;
    {
        const floatx4* wv4 = (const floatx4*)smwJ;
        wva = wv4[q * 2];     wvb = wv4[q * 2 + 1];
        wvc = wv4[8 + q * 2]; wvd = wv4[8 + q * 2 + 1];
    }
    __syncthreads();

    for (int t = 0; t < NSTEPS; ++t) {
        const floatx4* c4 = (const floatx4*)smC;
        floatx4 cva = c4[q*2], cvb = c4[q*2+1], cvc = c4[8+q*2], cvd = c4[8+q*2+1];

        floatx4 acc[4];
        #pragma unroll
        for (int nt = 0; nt < 4; ++nt) acc[nt] = (floatx4){0.f,0.f,0.f,0.f};

        if (t == 0) {
            // a0_i = b_i * wbi computed on the fly — no global a reads
            const floatx4* wb4 = (const floatx4*)smwbi;
            floatx4 bva = wb4[q*2], bvb = wb4[q*2+1], bvc = wb4[8+q*2], bvd = wb4[8+q*2+1];
            for (int c8 = 0; c8 < 4; ++c8) {
                int i = w * 64 + c8 * 16 + m;
                float Jij = smJ[i];
                float bi  = smB[i];
                floatx4 x0, x1, x2, x3;
                #pragma unroll
                for (int e = 0; e < 4; ++e) {
                    x0[e] = fmaxf(fmaf(Jij, wva[e], fmaf(bi, bva[e], cva[e])), 0.f);
                    x1[e] = fmaxf(fmaf(Jij, wvb[e], fmaf(bi, bvb[e], cvb[e])), 0.f);
                    x2[e] = fmaxf(fmaf(Jij, wvc[e], fmaf(bi, bvc[e], cvc[e])), 0.f);
                    x3[e] = fmaxf(fmaf(Jij, wvd[e], fmaf(bi, bvd[e], cvd[e])), 0.f);
                }
                union { short8 s; unsigned u[4]; } fa0, fa1;
                fa0.u[0] = pk2bf(x0[0], x0[1]); fa0.u[1] = pk2bf(x0[2], x0[3]);
                fa0.u[2] = pk2bf(x1[0], x1[1]); fa0.u[3] = pk2bf(x1[2], x1[3]);
                fa1.u[0] = pk2bf(x2[0], x2[1]); fa1.u[1] = pk2bf(x2[2], x2[3]);
                fa1.u[2] = pk2bf(x3[0], x3[1]); fa1.u[3] = pk2bf(x3[2], x3[3]);
                #pragma unroll
                for (int nt = 0; nt < 4; ++nt) {
                    floatx4 d = {0.f,0.f,0.f,0.f};
                    d = __builtin_amdgcn_mfma_f32_16x16x32_bf16(fa0.s, bfw[nt][0], d, 0, 0, 0);
                    d = __builtin_amdgcn_mfma_f32_16x16x32_bf16(fa1.s, bfw[nt][1], d, 0, 0, 0);
                    #pragma unroll
                    for (int r = 0; r < 4; ++r)
                        acc[nt][r] += fmaxf(d[r] + b2n[nt], 0.f);
                }
            }
        } else {
            const floatx4* a4 = (const floatx4*)(p.aBase + t * ABUFSZ);
            for (int c8 = 0; c8 < 4; ++c8) {
                int i = w * 64 + c8 * 16 + m;
                float Jij = smJ[i];
                floatx4 av0 = a4[i*16 + q*2],     av1 = a4[i*16 + q*2 + 1];
                floatx4 av2 = a4[i*16 + 8 + q*2], av3 = a4[i*16 + 8 + q*2 + 1];
                floatx4 x0, x1, x2, x3;
                #pragma unroll
                for (int e = 0; e < 4; ++e) {
                    x0[e] = fmaxf(fmaf(Jij, wva[e], av0[e]) + cva[e], 0.f);
                    x1[e] = fmaxf(fmaf(Jij, wvb[e], av1[e]) + cvb[e], 0.f);
                    x2[e] = fmaxf(fmaf(Jij, wvc[e], av2[e]) + cvc[e], 0.f);
                    x3[e] = fmaxf(fmaf(Jij, wvd[e], av3[e]) + cvd[e], 0.f);
                }
                union { short8 s; unsigned u[4]; } fa0, fa1;
                fa0.u[0] = pk2bf(x0[0], x0[1]); fa0.u[1] = pk2bf(x0[2], x0[3]);
                fa0.u[2] = pk2bf(x1[0], x1[1]); fa0.u[3] = pk2bf(x1[2], x1[3]);
                fa1.u[0] = pk2bf(x2[0], x2[1]); fa1.u[1] = pk2bf(x2[2], x2[3]);
                fa1.u[2] = pk2bf(x3[0], x3[1]); fa1.u[3] = pk2bf(x3[2], x3[3]);
                #pragma unroll
                for (int nt = 0; nt < 4; ++nt) {
                    floatx4 d = {0.f,0.f,0.f,0.f};
                    d = __builtin_amdgcn_mfma_f32_16x16x32_bf16(fa0.s, bfw[nt][0], d, 0, 0, 0);
                    d = __builtin_amdgcn_mfma_f32_16x16x32_bf16(fa1.s, bfw[nt][1], d, 0, 0, 0);
                    #pragma unroll
                    for (int r = 0; r < 4; ++r)
                        acc[nt][r] += fmaxf(d[r] + b2n[nt], 0.f);
                }
            }
        }

        // reduce rows within wave (8 waves); stage old h
        #pragma unroll
        for (int nt = 0; nt < 4; ++nt) {
            float v = acc[nt][0] + acc[nt][1] + acc[nt][2] + acc[nt][3];
            v += __shfl_xor(v, 16);
            v += __shfl_xor(v, 32);
            if (l < 16) smWave[w][nt*16 + l] = v;
        }
        if (tid < 16) smGin[tid] = smH[tid];
        __syncthreads();
        if (tid < 64) {
            float s = smWave[0][tid];
            #pragma unroll
            for (int ww = 1; ww < 8; ++ww) s += smWave[ww][tid];
            smMacc[tid] = s;
        }
        __syncthreads();

        // msg = W3 @ macc + 512*b3 : 32 outs x 16 partials = 512 threads
        {
            int o = tid >> 4, pp = tid & 15;
            const floatx4* W3v = (const floatx4*)p.W3;
            floatx4 wv0 = W3v[o*16 + pp];
            const floatx4* mac4 = (const floatx4*)smMacc;
            floatx4 mv = mac4[pp];
            float part = wv0[0]*mv[0] + wv0[1]*mv[1] + wv0[2]*mv[2] + wv0[3]*mv[3];
            part += __shfl_xor(part, 1);
            part += __shfl_xor(part, 2);
            part += __shfl_xor(part, 4);
            part += __shfl_xor(part, 8);
            if (pp == 0) smGin[16 + o] = part + 512.f * p.b3[o];
        }
        __syncthreads();

        // GRU gates
        if (tid < 192) {
            int o = tid >> 2, pp = tid & 3;
            const floatx4* Wv = (const floatx4*)p.W_ih;
            floatx4 w0 = Wv[o*12 + pp*3], w1 = Wv[o*12 + pp*3 + 1], w2 = Wv[o*12 + pp*3 + 2];
            int k0 = pp * 12;
            float part = 0.f;
            #pragma unroll
            for (int e = 0; e < 4; ++e) {
                part = fmaf(w0[e], smGin[k0 + e], part);
                part = fmaf(w1[e], smGin[k0 + 4 + e], part);
                part = fmaf(w2[e], smGin[k0 + 8 + e], part);
            }
            part += __shfl_xor(part, 1);
            part += __shfl_xor(part, 2);
            if (pp == 0) smGi[o] = part + p.b_ih[o];
        } else if (tid < 240) {
            int o = tid - 192;
            const floatx4* Wv = (const floatx4*)p.W_hh;
            floatx4 w0 = Wv[o*4], w1 = Wv[o*4+1], w2 = Wv[o*4+2], w3 = Wv[o*4+3];
            float s = p.b_hh[o];
            #pragma unroll
            for (int e = 0; e < 4; ++e) {
                s = fmaf(w0[e], smGin[e],      s);
                s = fmaf(w1[e], smGin[4 + e],  s);
                s = fmaf(w2[e], smGin[8 + e],  s);
                s = fmaf(w3[e], smGin[12 + e], s);
            }
            smGh[o] = s;
        }
        __syncthreads();

        if (tid < 16) {
            float r = 1.f / (1.f + __expf(-(smGi[tid] + smGh[tid])));
            float z = 1.f / (1.f + __expf(-(smGi[16+tid] + smGh[16+tid])));
            float n = tanhf(smGi[32+tid] + r * smGh[32+tid]);
            smH[tid] = (1.f - z) * n + z * smGin[tid];
        }
        __syncthreads();

        if (t < NSTEPS - 1) {
            // next projections: 0..63 -> smA, 64..127 -> smC
            if (tid < 128) {
                int o = tid & 63, sel = tid >> 6;
                const floatx4* Wv = (const floatx4*)(sel ? &smW1hj[0][0] : &smW1hi[0][0]);
                const floatx4* h4 = (const floatx4*)smH;
                floatx4 w0 = Wv[o*4], w1 = Wv[o*4+1], w2 = Wv[o*4+2], w3 = Wv[o*4+3];
                float s = 0.f;
                #pragma unroll
                for (int e = 0; e < 4; ++e) {
                    s = fmaf(w0[e], h4[0][e], s);
                    s = fmaf(w1[e], h4[1][e], s);
                    s = fmaf(w2[e], h4[2][e], s);
                    s = fmaf(w3[e], h4[3][e], s);
                }
                if (sel == 0) smA[o] = s + bj * smwbi[o];
                else          smC[o] = s + bj * smwbj[o] + smb1[o];
            }
            __syncthreads();
            if (tid < 16) {     // write-through a-row j into next rotation buffer
                float* aNext = p.aBase + (t + 1) * ABUFSZ;
                store_wt4(aNext + j * 64 + tid * 4, ((floatx4*)smA)[tid]);
            }
            gbar(p.bar, (unsigned)(t + 1));
        }
    }

    // ---- fused readout for node j ----
    if (tid < 64) {
        const floatx4* Wv = (const floatx4*)p.Wr1;
        const floatx4* h4 = (const floatx4*)smH;
        floatx4 w0 = Wv[tid*4], w1 = Wv[tid*4+1], w2 = Wv[tid*4+2], w3 = Wv[tid*4+3];
        float s = p.br1[tid];
        #pragma unroll
        for (int e = 0; e < 4; ++e) {
            s = fmaf(w0[e], h4[0][e], s);
            s = fmaf(w1[e], h4[1][e], s);
            s = fmaf(w2[e], h4[2][e], s);
            s = fmaf(w3[e], h4[3][e], s);
        }
        smY[tid] = fmaxf(s, 0.f);
    }
    __syncthreads();
    if (tid < 256) {
        int o = tid >> 2, pp = tid & 3;
        const floatx4* Wv = (const floatx4*)p.Wr2;
        floatx4 w0 = Wv[o*16 + pp*4],     w1 = Wv[o*16 + pp*4 + 1];
        floatx4 w2 = Wv[o*16 + pp*4 + 2], w3 = Wv[o*16 + pp*4 + 3];
        float part = 0.f;
        #pragma unroll
        for (int e = 0; e < 4; ++e) {
            part = fmaf(w0[e], smY[pp*16 + e],      part);
            part = fmaf(w1[e], smY[pp*16 + 4 + e],  part);
            part = fmaf(w2[e], smY[pp*16 + 8 + e],  part);
            part = fmaf(w3[e], smY[pp*16 + 12 + e], part);
        }
        part += __shfl_xor(part, 1);
        part += __shfl_xor(part, 2);
        if (pp == 0) smY2[o] = fmaxf(part + p.br2[o], 0.f);
    }
    __syncthreads();
    if (tid < 128) {
        int ot = tid >> 6, pp = tid & 63;
        float part = p.Wr3[ot*64 + pp] * smY2[pp];
        part += __shfl_xor(part, 1);
        part += __shfl_xor(part, 2);
        part += __shfl_xor(part, 4);
        part += __shfl_xor(part, 8);
        part += __shfl_xor(part, 16);
        part += __shfl_xor(part, 32);
        if (pp == 0) smR[ot] = part + p.br3[ot];
    }
    __syncthreads();
    if (tid == 0) {
        float e0 = 1.f / (1.f + __expf(-smR[0]));
        float e1 = 1.f / (1.f + __expf(-smR[1]));
        float tsum = e0 + e1;
        p.out[j*2]     = e0 / tsum;
        p.out[j*2 + 1] = e1 / tsum;
    }
}

extern "C" void kernel_launch(void* const* d_in, const int* in_sizes, int n_in,
                              void* d_out, int out_size, void* d_ws, size_t ws_size,
                              hipStream_t stream)
{
    Params par;
    par.J    = (const float*)d_in[0];
    par.b    = (const float*)d_in[1];
    par.W1   = (const float*)d_in[2];
    par.b1   = (const float*)d_in[3];
    par.W2   = (const float*)d_in[4];
    par.b2   = (const float*)d_in[5];
    par.W3   = (const float*)d_in[6];
    par.b3   = (const float*)d_in[7];
    par.W_ih = (const float*)d_in[8];
    par.b_ih = (const float*)d_in[9];
    par.W_hh = (const float*)d_in[10];
    par.b_hh = (const float*)d_in[11];
    par.Wr1  = (const float*)d_in[12];
    par.br1  = (const float*)d_in[13];
    par.Wr2  = (const float*)d_in[14];
    par.br2  = (const float*)d_in[15];
    par.Wr3  = (const float*)d_in[16];
    par.br3  = (const float*)d_in[17];
    par.out  = (float*)d_out;

    float* ws = (float*)d_ws;
    par.aBase = ws;                                   // 5 x 32768 floats
    par.bar   = (unsigned*)(ws + NSTEPS * ABUFSZ);

    hipMemsetAsync(par.bar, 0, 1024, stream);         // zero barrier state
    hipLaunchKernelGGL(ggnn_fused, dim3(512), dim3(512), 0, stream, par);
}